// Round 11
// baseline (311.832 us; speedup 1.0000x reference)
//
#include <hip/hip_runtime.h>
#include <hip/hip_bf16.h>

#define N_NODES 50000
#define N_EDGES 200000
#define NTILES  (N_EDGES / 32)      // 6250 tiles of 32 edges
#define EBLK    1024                // 4 blocks/CU (LDS 32.5 KB)
#define TWAVES  (EBLK * 4)          // 4096 persistent waves

typedef float  v2f    __attribute__((ext_vector_type(2)));
typedef float  f32x16 __attribute__((ext_vector_type(16)));
typedef short  s16x8  __attribute__((ext_vector_type(8)));

static __device__ inline v2f sp2(float s) { v2f r; r.x = s; r.y = s; return r; }

static __device__ inline v2f fma2(v2f a, v2f b, v2f c) {
#if __has_builtin(__builtin_elementwise_fma)
    return __builtin_elementwise_fma(a, b, c);
#else
    v2f r; r.x = fmaf(a.x, b.x, c.x); r.y = fmaf(a.y, b.y, c.y); return r;
#endif
}

static __device__ inline v2f max2(v2f a, v2f b) {
#if __has_builtin(__builtin_elementwise_max)
    return __builtin_elementwise_max(a, b);
#else
    v2f r; r.x = fmaxf(a.x, b.x); r.y = fmaxf(a.y, b.y); return r;
#endif
}

static __device__ inline unsigned short bf_rne(float f) {
    unsigned int u = __float_as_uint(f);
    u += 0x7fffu + ((u >> 16) & 1u);
    return (unsigned short)(u >> 16);
}

// ---------------------------------------------------------------------------
// CSR build: histogram -> single-block scan -> permutation
// ---------------------------------------------------------------------------
__global__ void hist_kernel(const int* __restrict__ ei, int* __restrict__ cnt)
{
    const int e = blockIdx.x * 256 + threadIdx.x;
    if (e < N_EDGES) atomicAdd(&cnt[ei[N_EDGES + e]], 1);
}

__global__ __launch_bounds__(1024) void scan_kernel(
    const int* __restrict__ cnt, int* __restrict__ off, int* __restrict__ cur)
{
    __shared__ int ps[1024];
    const int t = threadIdx.x;
    const int base = t * 49;                    // 1024*49 = 50176 >= 50000
    int s = 0;
    for (int j = 0; j < 49; ++j) {
        const int idx = base + j;
        if (idx < N_NODES) s += cnt[idx];
    }
    ps[t] = s;
    __syncthreads();
    for (int d = 1; d < 1024; d <<= 1) {        // Hillis-Steele inclusive
        const int v = (t >= d) ? ps[t - d] : 0;
        __syncthreads();
        ps[t] += v;
        __syncthreads();
    }
    int run = ps[t] - s;                        // exclusive prefix
    for (int j = 0; j < 49; ++j) {
        const int idx = base + j;
        if (idx < N_NODES) {
            off[idx] = run;
            cur[idx] = run;
            run += cnt[idx];
        }
    }
    if (t == 1023) off[N_NODES] = ps[1023];     // sentinel = N_EDGES
}

__global__ void perm_kernel(const int* __restrict__ ei, int* __restrict__ cur,
                            int* __restrict__ perm)
{
    const int e = blockIdx.x * 256 + threadIdx.x;
    if (e < N_EDGES) {
        const int s = atomicAdd(&cur[ei[N_EDGES + e]], 1);
        perm[s] = e;
    }
}

// ---------------------------------------------------------------------------
// Edge kernel (MFMA, atomic-free). Per 32-edge tile, per i (0..31):
//   D[o][e] = mfma_32x32x16_bf16(A, B);  msg[e][o] += x[src[e]][i]*relu(D[o][e])
// Output: msgbuf[e][0..31] fp32, written coalesced in edge order (full rows,
// no LDS transpose, no atomics). Lane (eo, hsel) owns feature quads
// {4h..}, {8+4h..}, {16+4h..}, {24+4h..} of edge eo -> 4 float4 stores.
// ---------------------------------------------------------------------------
__global__ __launch_bounds__(256, 4) void edge_kernel(
    const float* __restrict__ x, const int* __restrict__ ei,
    const float* __restrict__ ea, const float* __restrict__ nn_w,
    const float* __restrict__ nn_b, float* __restrict__ msgbuf)
{
    __shared__ unsigned short wT[1024 * 16];   // 32 KB: [col=i*32+o][16 bf16]

    // ---- prologue: weights -> bf16, K-layout [w0..w7 | w0..w6, bias] ----
    for (int c = threadIdx.x; c < 1024; c += 256) {
        unsigned short row[16];
#pragma unroll
        for (int k = 0; k < 8; ++k) row[k] = bf_rne(nn_w[k * 1024 + c]);
#pragma unroll
        for (int k = 0; k < 7; ++k) row[8 + k] = row[k];
        row[15] = bf_rne(nn_b[c]);
        unsigned int w[8];
#pragma unroll
        for (int q = 0; q < 8; ++q)
            w[q] = (unsigned int)row[2 * q] | ((unsigned int)row[2 * q + 1] << 16);
        uint4* p = (uint4*)(wT + c * 16);
        uint4 lo_; lo_.x = w[0]; lo_.y = w[1]; lo_.z = w[2]; lo_.w = w[3];
        uint4 hi_; hi_.x = w[4]; hi_.y = w[5]; hi_.z = w[6]; hi_.w = w[7];
        p[0] = lo_; p[1] = hi_;
    }
    __syncthreads();

    const int lane = threadIdx.x & 63;
    const int eo   = lane & 31;          // edge slot within tile
    const int hsel = lane >> 5;

    int t = (int)((blockIdx.x * 256u + threadIdx.x) >> 6);   // wave id = first tile
    if (t >= NTILES) return;

    // meta for tile t (src + edge_attr only; dst not needed here)
    int    sc  = ei[t * 32 + eo];
    float4 ea0 = ((const float4*)(ea + (size_t)(t * 32 + eo) * 8))[0];
    float4 ea1 = ((const float4*)(ea + (size_t)(t * 32 + eo) * 8))[1];

    float4 xq[8];
    {
        const float4* xp = (const float4*)(x + (size_t)sc * 32);
#pragma unroll
        for (int q = 0; q < 8; ++q) xq[q] = xp[q];
    }

    int tn = t + TWAVES;
    int tc = tn < NTILES ? tn : t;
    int    sn  = ei[tc * 32 + eo];
    float4 na0 = ((const float4*)(ea + (size_t)(tc * 32 + eo) * 8))[0];
    float4 na1 = ((const float4*)(ea + (size_t)(tc * 32 + eo) * 8))[1];

    const f32x16 zf = {0.f,0.f,0.f,0.f,0.f,0.f,0.f,0.f,
                       0.f,0.f,0.f,0.f,0.f,0.f,0.f,0.f};

    while (true) {
        // ---- B fragment: [ea_hi(8) | ea_lo(7), 1.0] ----
        const float ef[8] = {ea0.x, ea0.y, ea0.z, ea0.w,
                             ea1.x, ea1.y, ea1.z, ea1.w};
        s16x8 bfrag;
#pragma unroll
        for (int j = 0; j < 8; ++j) {
            const float f = ef[j];
            const unsigned short hi = bf_rne(f);
            unsigned short v;
            if (j < 7) {
                const unsigned short lo =
                    bf_rne(f - __uint_as_float(((unsigned int)hi) << 16));
                v = hsel ? lo : hi;
            } else {
                v = hsel ? (unsigned short)0x3F80 : hi;
            }
            bfrag[j] = (short)v;
        }

        const float4* xpn = (const float4*)(x + (size_t)sn * 32);

        v2f m2[8];
#pragma unroll
        for (int p = 0; p < 8; ++p) m2[p] = sp2(0.f);

        // ---- main loop: 32 MFMAs + packed relu/msg; x(t+1) prefetch fused ----
#pragma unroll
        for (int i = 0; i < 32; ++i) {
            const s16x8 a = *(const s16x8*)(wT + (i * 32 + eo) * 16 + hsel * 8);
            const f32x16 d =
                __builtin_amdgcn_mfma_f32_32x32x16_bf16(a, bfrag, zf, 0, 0, 0);
            const float4 xc = xq[i >> 2];
            const float xv = (i & 3) == 0 ? xc.x : (i & 3) == 1 ? xc.y
                           : (i & 3) == 2 ? xc.z : xc.w;
            const v2f x2 = sp2(xv);
#pragma unroll
            for (int p = 0; p < 8; ++p) {
                v2f dd; dd.x = d[2 * p]; dd.y = d[2 * p + 1];
                m2[p] = fma2(x2, max2(dd, sp2(0.f)), m2[p]);
            }
            if ((i & 3) == 3) xq[i >> 2] = xpn[i >> 2];   // prefetch next tile
        }

        // ---- coalesced row store: lane (eo,h) covers quads 4h,8+4h,16+4h,24+4h
        {
            float* mp = msgbuf + (size_t)(t * 32 + eo) * 32 + 4 * hsel;
            float4 s0; s0.x = m2[0].x; s0.y = m2[0].y; s0.z = m2[1].x; s0.w = m2[1].y;
            float4 s1; s1.x = m2[2].x; s1.y = m2[2].y; s1.z = m2[3].x; s1.w = m2[3].y;
            float4 s2; s2.x = m2[4].x; s2.y = m2[4].y; s2.z = m2[5].x; s2.w = m2[5].y;
            float4 s3; s3.x = m2[6].x; s3.y = m2[6].y; s3.z = m2[7].x; s3.w = m2[7].y;
            *(float4*)(mp)      = s0;
            *(float4*)(mp + 8)  = s1;
            *(float4*)(mp + 16) = s2;
            *(float4*)(mp + 24) = s3;
        }

        if (tn >= NTILES) break;
        t = tn; sc = sn; ea0 = na0; ea1 = na1;
        tn = t + TWAVES; tc = tn < NTILES ? tn : t;
        sn  = ei[tc * 32 + eo];
        na0 = ((const float4*)(ea + (size_t)(tc * 32 + eo) * 8))[0];
        na1 = ((const float4*)(ea + (size_t)(tc * 32 + eo) * 8))[1];
    }
}

// ---------------------------------------------------------------------------
// Finalize: one THREAD per node. Gather CSR rows perm[off[n]..off[n+1]) from
// msgbuf (L3-resident), then h = agg + x@root + bias -> LN -> relu -> lin.
// ---------------------------------------------------------------------------
__global__ __launch_bounds__(256) void finalize_kernel(
    const float* __restrict__ msgbuf, const int* __restrict__ off,
    const int* __restrict__ perm, const float* __restrict__ x,
    const float* __restrict__ root, const float* __restrict__ bias,
    const float* __restrict__ norm_w, const float* __restrict__ norm_b,
    const float* __restrict__ lin_w, const float* __restrict__ lin_b,
    float* __restrict__ out)
{
    __shared__ v2f rlds[512];            // root  [32 i][16 oo]
    __shared__ v2f llds[256];            // lin_w [32 o][8 jj]
    __shared__ v2f blds[16], nwl[16], nbl[16], lbl[8];

    const int t = threadIdx.x;
    for (int f = t; f < 1024; f += 256) ((float*)rlds)[f] = root[f];
    for (int f = t; f < 512;  f += 256) ((float*)llds)[f] = lin_w[f];
    if (t < 32) {
        ((float*)blds)[t] = bias[t];
        ((float*)nwl)[t]  = norm_w[t];
        ((float*)nbl)[t]  = norm_b[t];
    }
    if (t < 16) ((float*)lbl)[t] = lin_b[t];
    __syncthreads();

    const int n = blockIdx.x * 256 + t;
    if (n >= N_NODES) return;

    float4 xf[8];
    {
        const float4* xp = (const float4*)(x + (size_t)n * 32);
#pragma unroll
        for (int q = 0; q < 8; ++q) xf[q] = xp[q];
    }

    v2f h[16];
#pragma unroll
    for (int oo = 0; oo < 16; ++oo) h[oo] = blds[oo];

    {
        const int rs = off[n], re = off[n + 1];
        for (int r = rs; r < re; ++r) {
            const int e = perm[r];
            const float4* mp = (const float4*)(msgbuf + (size_t)e * 32);
#pragma unroll
            for (int q = 0; q < 8; ++q) {
                const float4 m = mp[q];
                v2f a; a.x = m.x; a.y = m.y;
                v2f b; b.x = m.z; b.y = m.w;
                h[2 * q]     += a;
                h[2 * q + 1] += b;
            }
        }
    }

#pragma unroll
    for (int i = 0; i < 32; ++i) {
        const float xi = ((const float*)xf)[i];
#pragma unroll
        for (int oo = 0; oo < 16; ++oo)
            h[oo] = fma2(sp2(xi), rlds[i * 16 + oo], h[oo]);
    }

    v2f sv = h[0];
#pragma unroll
    for (int oo = 1; oo < 16; ++oo) sv += h[oo];
    const float mu = (sv.x + sv.y) * (1.f / 32.f);
    const v2f mu2 = sp2(mu);
    v2f qv = (h[0] - mu2) * (h[0] - mu2);
#pragma unroll
    for (int oo = 1; oo < 16; ++oo) {
        const v2f dd = h[oo] - mu2;
        qv = fma2(dd, dd, qv);
    }
    const float var = (qv.x + qv.y) * (1.f / 32.f);
    const float rs2 = rsqrtf(var + 1e-5f);

    v2f r[16];
#pragma unroll
    for (int oo = 0; oo < 16; ++oo) {
        const v2f nv = fma2((h[oo] - mu2) * sp2(rs2), nwl[oo], nbl[oo]);
        r[oo] = max2(nv, sp2(0.f));
    }

    v2f a2[8];
#pragma unroll
    for (int jj = 0; jj < 8; ++jj) a2[jj] = lbl[jj];
#pragma unroll
    for (int o = 0; o < 32; ++o) {
        const float rv = (o & 1) ? r[o >> 1].y : r[o >> 1].x;
#pragma unroll
        for (int jj = 0; jj < 8; ++jj)
            a2[jj] = fma2(sp2(rv), llds[o * 8 + jj], a2[jj]);
    }

    float4* op = (float4*)(out + (size_t)n * 16);
#pragma unroll
    for (int q = 0; q < 4; ++q) {
        float4 v;
        v.x = a2[2 * q].x; v.y = a2[2 * q].y;
        v.z = a2[2 * q + 1].x; v.w = a2[2 * q + 1].y;
        op[q] = v;
    }
}

// ---------------------------------------------------------------------------
extern "C" void kernel_launch(void* const* d_in, const int* in_sizes, int n_in,
                              void* d_out, int out_size, void* d_ws, size_t ws_size,
                              hipStream_t stream)
{
    const float* x      = (const float*)d_in[0];
    const int*   ei     = (const int*)  d_in[1];
    const float* ea     = (const float*)d_in[2];
    const float* nn_w   = (const float*)d_in[3];
    const float* nn_b   = (const float*)d_in[4];
    const float* root   = (const float*)d_in[5];
    const float* bias   = (const float*)d_in[6];
    const float* norm_w = (const float*)d_in[7];
    const float* norm_b = (const float*)d_in[8];
    const float* lin_w  = (const float*)d_in[9];
    const float* lin_b  = (const float*)d_in[10];
    float* out = (float*)d_out;

    // ws layout: msgbuf (25.6 MB) | cnt | off(+sentinel) | cur | perm
    // (ws_size = 256 MiB per R10 profile; far above need)
    float* msgbuf = (float*)d_ws;
    int*   cnt    = (int*)((char*)d_ws + (size_t)N_EDGES * 32 * 4);
    int*   off    = cnt + 50000;
    int*   cur    = off + 50004;
    int*   perm   = cur + 50000;

    hipMemsetAsync(cnt, 0, (size_t)N_NODES * 4, stream);
    hist_kernel<<<(N_EDGES + 255) / 256, 256, 0, stream>>>(ei, cnt);
    scan_kernel<<<1, 1024, 0, stream>>>(cnt, off, cur);
    perm_kernel<<<(N_EDGES + 255) / 256, 256, 0, stream>>>(ei, cur, perm);
    edge_kernel<<<EBLK, 256, 0, stream>>>(x, ei, ea, nn_w, nn_b, msgbuf);
    finalize_kernel<<<(N_NODES + 255) / 256, 256, 0, stream>>>(
        msgbuf, off, perm, x, root, bias, norm_w, norm_b, lin_w, lin_b, out);
}

// Round 12
// 194.643 us; speedup vs baseline: 1.6021x; 1.6021x over previous
//
#include <hip/hip_runtime.h>
#include <hip/hip_bf16.h>

#define N_NODES 50000
#define N_EDGES 200000
#define NTILES  (N_EDGES / 32)      // 6250 tiles of 32 edges
#define EBLK    1024                // 4 blocks/CU (LDS 32.5 KB)
#define TWAVES  (EBLK * 4)          // 4096 persistent waves
#define SCAN_B  196                 // scan blocks: 196*256 = 50176 >= 50000

typedef float  v2f    __attribute__((ext_vector_type(2)));
typedef float  f32x16 __attribute__((ext_vector_type(16)));
typedef short  s16x8  __attribute__((ext_vector_type(8)));

static __device__ inline v2f sp2(float s) { v2f r; r.x = s; r.y = s; return r; }

static __device__ inline v2f fma2(v2f a, v2f b, v2f c) {
#if __has_builtin(__builtin_elementwise_fma)
    return __builtin_elementwise_fma(a, b, c);
#else
    v2f r; r.x = fmaf(a.x, b.x, c.x); r.y = fmaf(a.y, b.y, c.y); return r;
#endif
}

static __device__ inline v2f max2(v2f a, v2f b) {
#if __has_builtin(__builtin_elementwise_max)
    return __builtin_elementwise_max(a, b);
#else
    v2f r; r.x = fmaxf(a.x, b.x); r.y = fmaxf(a.y, b.y); return r;
#endif
}

static __device__ inline unsigned short bf_rne(float f) {
    unsigned int u = __float_as_uint(f);
    u += 0x7fffu + ((u >> 16) & 1u);
    return (unsigned short)(u >> 16);
}

// ---------------------------------------------------------------------------
// CSR build: histogram -> 3-kernel multi-block scan -> permutation
// ---------------------------------------------------------------------------
__global__ void hist_kernel(const int* __restrict__ ei, int* __restrict__ cnt)
{
    const int e = blockIdx.x * 256 + threadIdx.x;
    if (e < N_EDGES) atomicAdd(&cnt[ei[N_EDGES + e]], 1);
}

__global__ __launch_bounds__(256) void scan_local_kernel(
    const int* __restrict__ cnt, int* __restrict__ incl, int* __restrict__ bsum)
{
    __shared__ int ps[256];
    const int t = threadIdx.x;
    const int i = blockIdx.x * 256 + t;
    const int v = (i < N_NODES) ? cnt[i] : 0;
    ps[t] = v;
    __syncthreads();
#pragma unroll
    for (int d = 1; d < 256; d <<= 1) {
        const int u = (t >= d) ? ps[t - d] : 0;
        __syncthreads();
        ps[t] += u;
        __syncthreads();
    }
    incl[i] = ps[t];                       // incl sized SCAN_B*256, always in-bounds
    if (t == 255) bsum[blockIdx.x] = ps[255];
}

__global__ __launch_bounds__(256) void scan_bsum_kernel(
    const int* __restrict__ bsum, int* __restrict__ bex, int* __restrict__ off)
{
    __shared__ int ps[256];
    const int t = threadIdx.x;
    const int v = (t < SCAN_B) ? bsum[t] : 0;
    ps[t] = v;
    __syncthreads();
#pragma unroll
    for (int d = 1; d < 256; d <<= 1) {
        const int u = (t >= d) ? ps[t - d] : 0;
        __syncthreads();
        ps[t] += u;
        __syncthreads();
    }
    if (t < SCAN_B) bex[t] = ps[t] - v;    // exclusive block prefix
    if (t == 255) off[N_NODES] = ps[255];  // sentinel = N_EDGES
}

__global__ __launch_bounds__(256) void scan_final_kernel(
    const int* __restrict__ cnt, const int* __restrict__ incl,
    const int* __restrict__ bex, int* __restrict__ off, int* __restrict__ cur)
{
    const int i = blockIdx.x * 256 + threadIdx.x;
    if (i < N_NODES) {
        const int ex = incl[i] - cnt[i] + bex[blockIdx.x];
        off[i] = ex;
        cur[i] = ex;
    }
}

__global__ void perm_kernel(const int* __restrict__ ei, int* __restrict__ cur,
                            int* __restrict__ perm)
{
    const int e = blockIdx.x * 256 + threadIdx.x;
    if (e < N_EDGES) {
        const int s = atomicAdd(&cur[ei[N_EDGES + e]], 1);
        perm[s] = e;
    }
}

// ---------------------------------------------------------------------------
// Edge kernel (MFMA, atomic-free). Per 32-edge tile, per i (0..31):
//   D[o][e] = mfma_32x32x16_bf16(A, B);  msg[e][o] += x[src[e]][i]*relu(D[o][e])
// Output: msgbuf[e][0..31] fp32, coalesced full-row stores in edge order.
// ---------------------------------------------------------------------------
__global__ __launch_bounds__(256, 4) void edge_kernel(
    const float* __restrict__ x, const int* __restrict__ ei,
    const float* __restrict__ ea, const float* __restrict__ nn_w,
    const float* __restrict__ nn_b, float* __restrict__ msgbuf)
{
    __shared__ unsigned short wT[1024 * 16];   // 32 KB: [col=i*32+o][16 bf16]

    for (int c = threadIdx.x; c < 1024; c += 256) {
        unsigned short row[16];
#pragma unroll
        for (int k = 0; k < 8; ++k) row[k] = bf_rne(nn_w[k * 1024 + c]);
#pragma unroll
        for (int k = 0; k < 7; ++k) row[8 + k] = row[k];
        row[15] = bf_rne(nn_b[c]);
        unsigned int w[8];
#pragma unroll
        for (int q = 0; q < 8; ++q)
            w[q] = (unsigned int)row[2 * q] | ((unsigned int)row[2 * q + 1] << 16);
        uint4* p = (uint4*)(wT + c * 16);
        uint4 lo_; lo_.x = w[0]; lo_.y = w[1]; lo_.z = w[2]; lo_.w = w[3];
        uint4 hi_; hi_.x = w[4]; hi_.y = w[5]; hi_.z = w[6]; hi_.w = w[7];
        p[0] = lo_; p[1] = hi_;
    }
    __syncthreads();

    const int lane = threadIdx.x & 63;
    const int eo   = lane & 31;
    const int hsel = lane >> 5;

    int t = (int)((blockIdx.x * 256u + threadIdx.x) >> 6);
    if (t >= NTILES) return;

    int    sc  = ei[t * 32 + eo];
    float4 ea0 = ((const float4*)(ea + (size_t)(t * 32 + eo) * 8))[0];
    float4 ea1 = ((const float4*)(ea + (size_t)(t * 32 + eo) * 8))[1];

    float4 xq[8];
    {
        const float4* xp = (const float4*)(x + (size_t)sc * 32);
#pragma unroll
        for (int q = 0; q < 8; ++q) xq[q] = xp[q];
    }

    int tn = t + TWAVES;
    int tc = tn < NTILES ? tn : t;
    int    sn  = ei[tc * 32 + eo];
    float4 na0 = ((const float4*)(ea + (size_t)(tc * 32 + eo) * 8))[0];
    float4 na1 = ((const float4*)(ea + (size_t)(tc * 32 + eo) * 8))[1];

    const f32x16 zf = {0.f,0.f,0.f,0.f,0.f,0.f,0.f,0.f,
                       0.f,0.f,0.f,0.f,0.f,0.f,0.f,0.f};

    while (true) {
        const float ef[8] = {ea0.x, ea0.y, ea0.z, ea0.w,
                             ea1.x, ea1.y, ea1.z, ea1.w};
        s16x8 bfrag;
#pragma unroll
        for (int j = 0; j < 8; ++j) {
            const float f = ef[j];
            const unsigned short hi = bf_rne(f);
            unsigned short v;
            if (j < 7) {
                const unsigned short lo =
                    bf_rne(f - __uint_as_float(((unsigned int)hi) << 16));
                v = hsel ? lo : hi;
            } else {
                v = hsel ? (unsigned short)0x3F80 : hi;
            }
            bfrag[j] = (short)v;
        }

        const float4* xpn = (const float4*)(x + (size_t)sn * 32);

        v2f m2[8];
#pragma unroll
        for (int p = 0; p < 8; ++p) m2[p] = sp2(0.f);

#pragma unroll
        for (int i = 0; i < 32; ++i) {
            const s16x8 a = *(const s16x8*)(wT + (i * 32 + eo) * 16 + hsel * 8);
            const f32x16 d =
                __builtin_amdgcn_mfma_f32_32x32x16_bf16(a, bfrag, zf, 0, 0, 0);
            const float4 xc = xq[i >> 2];
            const float xv = (i & 3) == 0 ? xc.x : (i & 3) == 1 ? xc.y
                           : (i & 3) == 2 ? xc.z : xc.w;
            const v2f x2 = sp2(xv);
#pragma unroll
            for (int p = 0; p < 8; ++p) {
                v2f dd; dd.x = d[2 * p]; dd.y = d[2 * p + 1];
                m2[p] = fma2(x2, max2(dd, sp2(0.f)), m2[p]);
            }
            if ((i & 3) == 3) xq[i >> 2] = xpn[i >> 2];
        }

        {
            float* mp = msgbuf + (size_t)(t * 32 + eo) * 32 + 4 * hsel;
            float4 s0; s0.x = m2[0].x; s0.y = m2[0].y; s0.z = m2[1].x; s0.w = m2[1].y;
            float4 s1; s1.x = m2[2].x; s1.y = m2[2].y; s1.z = m2[3].x; s1.w = m2[3].y;
            float4 s2; s2.x = m2[4].x; s2.y = m2[4].y; s2.z = m2[5].x; s2.w = m2[5].y;
            float4 s3; s3.x = m2[6].x; s3.y = m2[6].y; s3.z = m2[7].x; s3.w = m2[7].y;
            *(float4*)(mp)      = s0;
            *(float4*)(mp + 8)  = s1;
            *(float4*)(mp + 16) = s2;
            *(float4*)(mp + 24) = s3;
        }

        if (tn >= NTILES) break;
        t = tn; sc = sn; ea0 = na0; ea1 = na1;
        tn = t + TWAVES; tc = tn < NTILES ? tn : t;
        sn  = ei[tc * 32 + eo];
        na0 = ((const float4*)(ea + (size_t)(tc * 32 + eo) * 8))[0];
        na1 = ((const float4*)(ea + (size_t)(tc * 32 + eo) * 8))[1];
    }
}

// ---------------------------------------------------------------------------
// Finalize: one THREAD per node. Gather CSR rows perm[off[n]..off[n+1]) from
// msgbuf (L3-resident), then h = agg + x@root + bias -> LN -> relu -> lin.
// ---------------------------------------------------------------------------
__global__ __launch_bounds__(256) void finalize_kernel(
    const float* __restrict__ msgbuf, const int* __restrict__ off,
    const int* __restrict__ perm, const float* __restrict__ x,
    const float* __restrict__ root, const float* __restrict__ bias,
    const float* __restrict__ norm_w, const float* __restrict__ norm_b,
    const float* __restrict__ lin_w, const float* __restrict__ lin_b,
    float* __restrict__ out)
{
    __shared__ v2f rlds[512];            // root  [32 i][16 oo]
    __shared__ v2f llds[256];            // lin_w [32 o][8 jj]
    __shared__ v2f blds[16], nwl[16], nbl[16], lbl[8];

    const int t = threadIdx.x;
    for (int f = t; f < 1024; f += 256) ((float*)rlds)[f] = root[f];
    for (int f = t; f < 512;  f += 256) ((float*)llds)[f] = lin_w[f];
    if (t < 32) {
        ((float*)blds)[t] = bias[t];
        ((float*)nwl)[t]  = norm_w[t];
        ((float*)nbl)[t]  = norm_b[t];
    }
    if (t < 16) ((float*)lbl)[t] = lin_b[t];
    __syncthreads();

    const int n = blockIdx.x * 256 + t;
    if (n >= N_NODES) return;

    float4 xf[8];
    {
        const float4* xp = (const float4*)(x + (size_t)n * 32);
#pragma unroll
        for (int q = 0; q < 8; ++q) xf[q] = xp[q];
    }

    v2f h[16];
#pragma unroll
    for (int oo = 0; oo < 16; ++oo) h[oo] = blds[oo];

    {
        const int rs = off[n], re = off[n + 1];
        for (int r = rs; r < re; ++r) {
            const int e = perm[r];
            const float4* mp = (const float4*)(msgbuf + (size_t)e * 32);
#pragma unroll
            for (int q = 0; q < 8; ++q) {
                const float4 m = mp[q];
                v2f a; a.x = m.x; a.y = m.y;
                v2f b; b.x = m.z; b.y = m.w;
                h[2 * q]     += a;
                h[2 * q + 1] += b;
            }
        }
    }

#pragma unroll
    for (int i = 0; i < 32; ++i) {
        const float xi = ((const float*)xf)[i];
#pragma unroll
        for (int oo = 0; oo < 16; ++oo)
            h[oo] = fma2(sp2(xi), rlds[i * 16 + oo], h[oo]);
    }

    v2f sv = h[0];
#pragma unroll
    for (int oo = 1; oo < 16; ++oo) sv += h[oo];
    const float mu = (sv.x + sv.y) * (1.f / 32.f);
    const v2f mu2 = sp2(mu);
    v2f qv = (h[0] - mu2) * (h[0] - mu2);
#pragma unroll
    for (int oo = 1; oo < 16; ++oo) {
        const v2f dd = h[oo] - mu2;
        qv = fma2(dd, dd, qv);
    }
    const float var = (qv.x + qv.y) * (1.f / 32.f);
    const float rs2 = rsqrtf(var + 1e-5f);

    v2f r[16];
#pragma unroll
    for (int oo = 0; oo < 16; ++oo) {
        const v2f nv = fma2((h[oo] - mu2) * sp2(rs2), nwl[oo], nbl[oo]);
        r[oo] = max2(nv, sp2(0.f));
    }

    v2f a2[8];
#pragma unroll
    for (int jj = 0; jj < 8; ++jj) a2[jj] = lbl[jj];
#pragma unroll
    for (int o = 0; o < 32; ++o) {
        const float rv = (o & 1) ? r[o >> 1].y : r[o >> 1].x;
#pragma unroll
        for (int jj = 0; jj < 8; ++jj)
            a2[jj] = fma2(sp2(rv), llds[o * 8 + jj], a2[jj]);
    }

    float4* op = (float4*)(out + (size_t)n * 16);
#pragma unroll
    for (int q = 0; q < 4; ++q) {
        float4 v;
        v.x = a2[2 * q].x; v.y = a2[2 * q].y;
        v.z = a2[2 * q + 1].x; v.w = a2[2 * q + 1].y;
        op[q] = v;
    }
}

// ---------------------------------------------------------------------------
extern "C" void kernel_launch(void* const* d_in, const int* in_sizes, int n_in,
                              void* d_out, int out_size, void* d_ws, size_t ws_size,
                              hipStream_t stream)
{
    const float* x      = (const float*)d_in[0];
    const int*   ei     = (const int*)  d_in[1];
    const float* ea     = (const float*)d_in[2];
    const float* nn_w   = (const float*)d_in[3];
    const float* nn_b   = (const float*)d_in[4];
    const float* root   = (const float*)d_in[5];
    const float* bias   = (const float*)d_in[6];
    const float* norm_w = (const float*)d_in[7];
    const float* norm_b = (const float*)d_in[8];
    const float* lin_w  = (const float*)d_in[9];
    const float* lin_b  = (const float*)d_in[10];
    float* out = (float*)d_out;

    // ws layout: msgbuf (25.6 MB) | cnt | off(+sent) | cur | perm | incl | bsum | bex
    float* msgbuf = (float*)d_ws;
    int*   cnt    = (int*)((char*)d_ws + (size_t)N_EDGES * 32 * 4);
    int*   off    = cnt + 50000;
    int*   cur    = off + 50004;
    int*   perm   = cur + 50000;
    int*   incl   = perm + 200000;
    int*   bsum   = incl + SCAN_B * 256;
    int*   bex    = bsum + 256;

    hipMemsetAsync(cnt, 0, (size_t)N_NODES * 4, stream);
    hist_kernel<<<(N_EDGES + 255) / 256, 256, 0, stream>>>(ei, cnt);
    scan_local_kernel<<<SCAN_B, 256, 0, stream>>>(cnt, incl, bsum);
    scan_bsum_kernel<<<1, 256, 0, stream>>>(bsum, bex, off);
    scan_final_kernel<<<SCAN_B, 256, 0, stream>>>(cnt, incl, bex, off, cur);
    perm_kernel<<<(N_EDGES + 255) / 256, 256, 0, stream>>>(ei, cur, perm);
    edge_kernel<<<EBLK, 256, 0, stream>>>(x, ei, ea, nn_w, nn_b, msgbuf);
    finalize_kernel<<<(N_NODES + 255) / 256, 256, 0, stream>>>(
        msgbuf, off, perm, x, root, bias, norm_w, norm_b, lin_w, lin_b, out);
}